// Round 2
// baseline (1343.278 us; speedup 1.0000x reference)
//
#include <hip/hip_runtime.h>
#include <hip/hip_bf16.h>

#define T_TOK 4096
#define D_MODEL 1024
#define I_DIM 2048
#define E_EXP 16

typedef __bf16 bf16x8 __attribute__((ext_vector_type(8)));
typedef float f32x4 __attribute__((ext_vector_type(4)));

__device__ __forceinline__ bf16x8 pack8(f32x4 a, f32x4 b) {
    bf16x8 r;
    r[0] = (__bf16)a[0]; r[1] = (__bf16)a[1]; r[2] = (__bf16)a[2]; r[3] = (__bf16)a[3];
    r[4] = (__bf16)b[0]; r[5] = (__bf16)b[1]; r[6] = (__bf16)b[2]; r[7] = (__bf16)b[3];
    return r;
}

// async global->LDS, 16B per lane; dst must be wave-uniform base (HW adds lane*16)
__device__ __forceinline__ void gl2lds(const __bf16* src, __bf16* dst) {
    __builtin_amdgcn_global_load_lds(
        (const __attribute__((address_space(1))) unsigned int*)src,
        (__attribute__((address_space(3))) unsigned int*)dst, 16, 0, 0);
}

// ---------------- fp32 -> bf16 streaming convert ----------------
__global__ __launch_bounds__(256) void cvt_kernel(
    const float* __restrict__ in, __bf16* __restrict__ out, int n8)
{
    const int stride = gridDim.x * 256;
    for (int i = blockIdx.x * 256 + threadIdx.x; i < n8; i += stride) {
        f32x4 a = ((const f32x4*)in)[i * 2];
        f32x4 b = ((const f32x4*)in)[i * 2 + 1];
        ((bf16x8*)out)[i] = pack8(a, b);
    }
}

// ---------------- Router: fp64-accum logits, top-4, softmax-over-top4 ----------------
__global__ __launch_bounds__(256) void router_kernel(
    const float* __restrict__ x, const float* __restrict__ rw,
    int* __restrict__ counts, int* __restrict__ tok_list, float* __restrict__ gate_list)
{
    const int wid = threadIdx.x >> 6, lane = threadIdx.x & 63;
    const int t = blockIdx.x * 4 + wid;
    const int e = lane & 15, part = lane >> 4;

    const float* xr = x + (size_t)t * D_MODEL + part * 256;
    const float* wr = rw + (size_t)e * D_MODEL + part * 256;
    double acc = 0.0;
    #pragma unroll 4
    for (int i = 0; i < 256; i += 4) {
        f32x4 xv = *(const f32x4*)(xr + i);
        f32x4 wv = *(const f32x4*)(wr + i);
        acc += (double)xv[0] * wv[0] + (double)xv[1] * wv[1]
             + (double)xv[2] * wv[2] + (double)xv[3] * wv[3];
    }
    acc += __shfl_xor(acc, 16, 64);
    acc += __shfl_xor(acc, 32, 64);

    __shared__ float logits[4][16];
    if (lane < 16) logits[wid][lane] = (float)acc;
    __syncthreads();

    if (lane == 0) {
        float l[16];
        #pragma unroll
        for (int i = 0; i < 16; i++) l[i] = logits[wid][i];
        int idx[4]; float val[4];
        unsigned taken = 0;
        for (int k = 0; k < 4; k++) {
            int best = 0; float bv = -1e30f;
            for (int i = 0; i < 16; i++)
                if (!((taken >> i) & 1) && l[i] > bv) { bv = l[i]; best = i; }
            idx[k] = best; val[k] = bv; taken |= (1u << best);
        }
        float m = val[0];
        float w[4], s = 0.f;
        for (int k = 0; k < 4; k++) { w[k] = __expf(val[k] - m); s += w[k]; }
        for (int k = 0; k < 4; k++) {
            int ee = idx[k];
            int slot = atomicAdd(&counts[ee], 1);
            tok_list[ee * T_TOK + slot] = t;
            gate_list[ee * T_TOK + slot] = w[k] / s;
        }
    }
}

__global__ void prefix_kernel(const int* __restrict__ counts, int* __restrict__ prefix) {
    if (threadIdx.x == 0) {
        int acc = 0;
        for (int e = 0; e < E_EXP; e++) { prefix[e] = acc; acc += (counts[e] + 127) & ~127; }
        prefix[E_EXP] = acc;
    }
}

// ---------------- GEMM1 + SwiGLU: 128 tok x (64 w1 + 64 v1) cols, BK=32, gl_lds staging.
// LDS linear [128][32] bf16; chunk swizzle (row>>1)&3 baked into SRC addr + ds_read addr.
__global__ __launch_bounds__(256) void gemm1_kernel(
    const __bf16* __restrict__ xb, const __bf16* __restrict__ wsb,
    const int* __restrict__ counts, const int* __restrict__ prefix,
    const int* __restrict__ tok_list, __bf16* __restrict__ act)
{
    const int e = blockIdx.z;
    const int count = counts[e];
    const int tileM = blockIdx.x;                 // tileM fastest: co-resident blocks share B panel
    if (tileM * 128 >= count) return;
    const int tileN = blockIdx.y;

    const int tid = threadIdx.x;
    const int lane = tid & 63, wid = tid >> 6;
    const int l15 = lane & 15, q = lane >> 4;
    const int wr = wid >> 1, wc = wid & 1;

    __shared__ __bf16 As[2][128 * 32];
    __shared__ __bf16 Bs[2][128 * 32];

    // staging: issue j covers LDS rows wid*32 + j*16 + (lane>>2), phys chunk lane&3
    const int sch = ((lane & 3) ^ ((lane >> 3) & 3)) * 8;   // logical chunk to fetch
    const __bf16* srcA[2]; const __bf16* srcB[2];
    #pragma unroll
    for (int j = 0; j < 2; ++j) {
        const int row = wid * 32 + j * 16 + (lane >> 2);
        const int gr = tileM * 128 + row;
        const int grc = gr < count ? gr : count - 1;
        const int token = tok_list[e * T_TOK + grc];
        srcA[j] = xb + (size_t)token * D_MODEL + sch;
        const int gcol = (row < 64) ? (tileN * 64 + row) : (I_DIM + tileN * 64 + row - 64);
        srcB[j] = wsb + ((size_t)e * 2 * I_DIM + gcol) * D_MODEL + sch;
    }

    f32x4 acc[4][4];
    const f32x4 z = {0.f, 0.f, 0.f, 0.f};
    #pragma unroll
    for (int mi = 0; mi < 4; ++mi)
        #pragma unroll
        for (int nj = 0; nj < 4; ++nj) acc[mi][nj] = z;

    const int rdch = (q ^ ((l15 >> 1) & 3)) * 8;
    const int aoff  = (wr * 64 + l15) * 32 + rdch;   // + mi*512
    const int boff  = (wc * 32 + l15) * 32 + rdch;   // w1: +nj*512 ; v1: +2048+nj*512

    #define STAGE1(bufi, koff) do { \
        gl2lds(srcA[0] + (koff), &As[bufi][wid * 1024]); \
        gl2lds(srcA[1] + (koff), &As[bufi][wid * 1024 + 512]); \
        gl2lds(srcB[0] + (koff), &Bs[bufi][wid * 1024]); \
        gl2lds(srcB[1] + (koff), &Bs[bufi][wid * 1024 + 512]); \
    } while (0)

    STAGE1(0, 0);
    __syncthreads();

    for (int s = 0; s < 32; ++s) {
        const int cur = s & 1;
        if (s + 1 < 32) STAGE1(cur ^ 1, (s + 1) * 32);
        bf16x8 a[4], b[4];
        #pragma unroll
        for (int mi = 0; mi < 4; ++mi) a[mi] = *(const bf16x8*)&As[cur][aoff + mi * 512];
        #pragma unroll
        for (int nj = 0; nj < 2; ++nj) {
            b[nj]     = *(const bf16x8*)&Bs[cur][boff + nj * 512];
            b[nj + 2] = *(const bf16x8*)&Bs[cur][boff + 2048 + nj * 512];
        }
        #pragma unroll
        for (int mi = 0; mi < 4; ++mi)
            #pragma unroll
            for (int nj = 0; nj < 4; ++nj)
                acc[mi][nj] = __builtin_amdgcn_mfma_f32_16x16x32_bf16(a[mi], b[nj], acc[mi][nj], 0, 0, 0);
        __syncthreads();
    }
    #undef STAGE1

    const int abase = prefix[e];
    #pragma unroll
    for (int mi = 0; mi < 4; ++mi) {
        #pragma unroll
        for (int j = 0; j < 4; ++j) {
            const int grow = tileM * 128 + wr * 64 + mi * 16 + q * 4 + j;
            if (grow < count) {
                __bf16* arow = act + (size_t)(abase + grow) * I_DIM + tileN * 64 + wc * 32 + l15;
                #pragma unroll
                for (int nj = 0; nj < 2; ++nj) {
                    const float v1 = acc[mi][nj][j];
                    const float v2 = acc[mi][nj + 2][j];
                    arow[nj * 16] = (__bf16)(v1 / (1.f + __expf(-v1)) * v2);
                }
            }
        }
    }
}

// ---------------- GEMM2: y = act @ w2^T (bf16), K=2048, atomic scatter of gate*y ----------
__global__ __launch_bounds__(256) void gemm2_kernel(
    const __bf16* __restrict__ act, const __bf16* __restrict__ w2b,
    const int* __restrict__ counts, const int* __restrict__ prefix,
    const int* __restrict__ tok_list, const float* __restrict__ gate_list,
    float* __restrict__ out)
{
    const int e = blockIdx.z;
    const int count = counts[e];
    const int tileM = blockIdx.x;
    if (tileM * 128 >= count) return;
    const int tileN = blockIdx.y;

    const int tid = threadIdx.x;
    const int lane = tid & 63, wid = tid >> 6;
    const int l15 = lane & 15, q = lane >> 4;
    const int wr = wid >> 1, wc = wid & 1;
    const int abase = prefix[e];

    __shared__ __bf16 As[2][128 * 32];
    __shared__ __bf16 Bs[2][128 * 32];

    const int sch = ((lane & 3) ^ ((lane >> 3) & 3)) * 8;
    const __bf16* srcA[2]; const __bf16* srcB[2];
    #pragma unroll
    for (int j = 0; j < 2; ++j) {
        const int row = wid * 32 + j * 16 + (lane >> 2);
        srcA[j] = act + (size_t)(abase + tileM * 128 + row) * I_DIM + sch;
        srcB[j] = w2b + ((size_t)e * D_MODEL + tileN * 128 + row) * I_DIM + sch;
    }

    f32x4 acc[4][4];
    const f32x4 z = {0.f, 0.f, 0.f, 0.f};
    #pragma unroll
    for (int mi = 0; mi < 4; ++mi)
        #pragma unroll
        for (int nj = 0; nj < 4; ++nj) acc[mi][nj] = z;

    const int rdch = (q ^ ((l15 >> 1) & 3)) * 8;
    const int aoff = (wr * 64 + l15) * 32 + rdch;
    const int boff = (wc * 64 + l15) * 32 + rdch;

    #define STAGE2(bufi, koff) do { \
        gl2lds(srcA[0] + (koff), &As[bufi][wid * 1024]); \
        gl2lds(srcA[1] + (koff), &As[bufi][wid * 1024 + 512]); \
        gl2lds(srcB[0] + (koff), &Bs[bufi][wid * 1024]); \
        gl2lds(srcB[1] + (koff), &Bs[bufi][wid * 1024 + 512]); \
    } while (0)

    STAGE2(0, 0);
    __syncthreads();

    for (int s = 0; s < 64; ++s) {
        const int cur = s & 1;
        if (s + 1 < 64) STAGE2(cur ^ 1, (s + 1) * 32);
        bf16x8 a[4], b[4];
        #pragma unroll
        for (int mi = 0; mi < 4; ++mi) a[mi] = *(const bf16x8*)&As[cur][aoff + mi * 512];
        #pragma unroll
        for (int nj = 0; nj < 4; ++nj) b[nj] = *(const bf16x8*)&Bs[cur][boff + nj * 512];
        #pragma unroll
        for (int mi = 0; mi < 4; ++mi)
            #pragma unroll
            for (int nj = 0; nj < 4; ++nj)
                acc[mi][nj] = __builtin_amdgcn_mfma_f32_16x16x32_bf16(a[mi], b[nj], acc[mi][nj], 0, 0, 0);
        __syncthreads();
    }
    #undef STAGE2

    #pragma unroll
    for (int mi = 0; mi < 4; ++mi) {
        #pragma unroll
        for (int j = 0; j < 4; ++j) {
            const int grow = tileM * 128 + wr * 64 + mi * 16 + q * 4 + j;
            if (grow < count) {
                const int token = tok_list[e * T_TOK + grow];
                const float gate = gate_list[e * T_TOK + grow];
                float* orow = out + (size_t)token * D_MODEL + tileN * 128 + wc * 64 + l15;
                #pragma unroll
                for (int nj = 0; nj < 4; ++nj)
                    atomicAdd(orow + nj * 16, gate * acc[mi][nj][j]);
            }
        }
    }
}

extern "C" void kernel_launch(void* const* d_in, const int* in_sizes, int n_in,
                              void* d_out, int out_size, void* d_ws, size_t ws_size,
                              hipStream_t stream)
{
    const float* x   = (const float*)d_in[0];   // [4096, 1024]
    const float* rw  = (const float*)d_in[1];   // [16, 1024]
    const float* wsw = (const float*)d_in[2];   // [16, 4096, 1024]
    const float* w2s = (const float*)d_in[3];   // [16, 1024, 2048]
    float* out = (float*)d_out;                 // [4096, 1024] fp32

    char* wsb = (char*)d_ws;
    int* counts      = (int*)wsb;                                  // 64 B
    int* prefix      = (int*)(wsb + 128);                          // 17 ints
    int* tok_list    = (int*)(wsb + 1024);                         // 256 KB
    float* gate_list = (float*)(wsb + 1024 + E_EXP * T_TOK * 4);   // 256 KB
    __bf16* x_bf     = (__bf16*)(wsb + (1u << 20));                // 8 MB, [1,9) MB
    __bf16* act      = (__bf16*)(wsb + (16u << 20));               // 75.5 MB, [16,88) MB
    __bf16* ws_bf    = (__bf16*)(wsb + (96u << 20));               // 134 MB, [96,224) MB
    __bf16* w2_bf    = ws_bf;                                      // aliased: written after gemm1

    hipMemsetAsync(counts, 0, E_EXP * sizeof(int), stream);
    hipMemsetAsync(d_out, 0, (size_t)out_size * sizeof(float), stream);

    router_kernel<<<dim3(T_TOK / 4), 256, 0, stream>>>(x, rw, counts, tok_list, gate_list);
    prefix_kernel<<<1, 64, 0, stream>>>(counts, prefix);

    cvt_kernel<<<2048, 256, 0, stream>>>(x, x_bf, T_TOK * D_MODEL / 8);
    cvt_kernel<<<8192, 256, 0, stream>>>(wsw, ws_bf, E_EXP * 2 * I_DIM * D_MODEL / 8);

    gemm1_kernel<<<dim3(T_TOK / 128, I_DIM / 64, E_EXP), 256, 0, stream>>>(
        x_bf, ws_bf, counts, prefix, tok_list, act);

    cvt_kernel<<<8192, 256, 0, stream>>>(w2s, w2_bf, E_EXP * D_MODEL * I_DIM / 8);

    gemm2_kernel<<<dim3(T_TOK / 128, D_MODEL / 128, E_EXP), 256, 0, stream>>>(
        act, w2_bf, counts, prefix, tok_list, gate_list, out);
}

// Round 3
// 814.225 us; speedup vs baseline: 1.6498x; 1.6498x over previous
//
#include <hip/hip_runtime.h>
#include <hip/hip_bf16.h>

#define T_TOK 4096
#define D_MODEL 1024
#define I_DIM 2048
#define E_EXP 16

typedef __bf16 bf16x8 __attribute__((ext_vector_type(8)));
typedef float f32x4 __attribute__((ext_vector_type(4)));

__device__ __forceinline__ bf16x8 pack8(f32x4 a, f32x4 b) {
    bf16x8 r;
    r[0] = (__bf16)a[0]; r[1] = (__bf16)a[1]; r[2] = (__bf16)a[2]; r[3] = (__bf16)a[3];
    r[4] = (__bf16)b[0]; r[5] = (__bf16)b[1]; r[6] = (__bf16)b[2]; r[7] = (__bf16)b[3];
    return r;
}

__device__ __forceinline__ void gl2lds(const __bf16* src, __bf16* dst) {
    __builtin_amdgcn_global_load_lds(
        (const __attribute__((address_space(1))) unsigned int*)src,
        (__attribute__((address_space(3))) unsigned int*)dst, 16, 0, 0);
}

__global__ __launch_bounds__(256) void cvt_kernel(
    const float* __restrict__ in, __bf16* __restrict__ out, int n8)
{
    const int stride = gridDim.x * 256;
    for (int i = blockIdx.x * 256 + threadIdx.x; i < n8; i += stride) {
        f32x4 a = ((const f32x4*)in)[i * 2];
        f32x4 b = ((const f32x4*)in)[i * 2 + 1];
        ((bf16x8*)out)[i] = pack8(a, b);
    }
}

// ---------------- Router: fp64-accum logits, top-4, softmax-over-top4 ----------------
__global__ __launch_bounds__(256) void router_kernel(
    const float* __restrict__ x, const float* __restrict__ rw,
    int* __restrict__ counts, int* __restrict__ tok_list, float* __restrict__ gate_list)
{
    const int wid = threadIdx.x >> 6, lane = threadIdx.x & 63;
    const int t = blockIdx.x * 4 + wid;
    const int e = lane & 15, part = lane >> 4;

    const float* xr = x + (size_t)t * D_MODEL + part * 256;
    const float* wr = rw + (size_t)e * D_MODEL + part * 256;
    double acc = 0.0;
    #pragma unroll 4
    for (int i = 0; i < 256; i += 4) {
        f32x4 xv = *(const f32x4*)(xr + i);
        f32x4 wv = *(const f32x4*)(wr + i);
        acc += (double)xv[0] * wv[0] + (double)xv[1] * wv[1]
             + (double)xv[2] * wv[2] + (double)xv[3] * wv[3];
    }
    acc += __shfl_xor(acc, 16, 64);
    acc += __shfl_xor(acc, 32, 64);

    __shared__ float logits[4][16];
    if (lane < 16) logits[wid][lane] = (float)acc;
    __syncthreads();

    if (lane == 0) {
        float l[16];
        #pragma unroll
        for (int i = 0; i < 16; i++) l[i] = logits[wid][i];
        int idx[4]; float val[4];
        unsigned taken = 0;
        for (int k = 0; k < 4; k++) {
            int best = 0; float bv = -1e30f;
            for (int i = 0; i < 16; i++)
                if (!((taken >> i) & 1) && l[i] > bv) { bv = l[i]; best = i; }
            idx[k] = best; val[k] = bv; taken |= (1u << best);
        }
        float m = val[0];
        float w[4], s = 0.f;
        for (int k = 0; k < 4; k++) { w[k] = __expf(val[k] - m); s += w[k]; }
        for (int k = 0; k < 4; k++) {
            int ee = idx[k];
            int slot = atomicAdd(&counts[ee], 1);
            tok_list[ee * T_TOK + slot] = t;
            gate_list[ee * T_TOK + slot] = w[k] / s;
        }
    }
}

__global__ void prefix_kernel(const int* __restrict__ counts, int* __restrict__ prefix) {
    if (threadIdx.x == 0) {
        int acc = 0;
        for (int e = 0; e < E_EXP; e++) { prefix[e] = acc; acc += (counts[e] + 255) & ~255; }
        prefix[E_EXP] = acc;
    }
}

// ======================= GEMM1 + SwiGLU =======================
// 256 tokens x 256 B-rows (=128 act cols paired w1/v1), BK=64, 8 waves (2M x 4N).
// Counted-vmcnt 3-deep pipeline, 2 raw barriers/tile. 8-chunk XOR swizzle on
// both gl_lds SOURCE and ds_read addr (LDS itself linear [row][64]).
__global__ __launch_bounds__(512) void gemm1_kernel(
    const __bf16* __restrict__ xb, const __bf16* __restrict__ wsb,
    const int* __restrict__ counts, const int* __restrict__ prefix,
    const int* __restrict__ tok_list, __bf16* __restrict__ act)
{
    const int e = blockIdx.z;
    const int count = counts[e];
    const int tileM = blockIdx.x;
    if (tileM * 256 >= count) return;
    const int tileN = blockIdx.y;

    const int tid = threadIdx.x;
    const int lane = tid & 63, w = tid >> 6;
    const int l15 = lane & 15, q = lane >> 4, l7 = lane & 7;
    const int wm = w >> 2, wn = w & 3;

    __shared__ __bf16 As[2][256 * 64];
    __shared__ __bf16 Bs[2][256 * 64];

    // ---- staging sources: waves 0-3 stage A (64 rows each), 4-7 stage B ----
    const int rl = lane >> 3;               // row within 8-row issue group
    const int lc = (lane & 7) ^ rl;         // logical 16B chunk (swizzle involution)
    const __bf16* ptr[8];
    if (w < 4) {
        #pragma unroll
        for (int i = 0; i < 8; ++i) {
            int grow = tileM * 256 + w * 64 + i * 8 + rl;
            if (grow >= count) grow = count - 1;
            const int token = tok_list[e * T_TOK + grow];
            ptr[i] = xb + (size_t)token * D_MODEL + lc * 8;
        }
    } else {
        const int w4 = w - 4;
        #pragma unroll
        for (int i = 0; i < 8; ++i) {
            const int sub = i * 8 + rl;
            const int gcol = (sub < 32) ? (tileN * 128 + w4 * 32 + sub)
                                        : (I_DIM + tileN * 128 + w4 * 32 + (sub - 32));
            ptr[i] = wsb + ((size_t)e * 2 * I_DIM + gcol) * D_MODEL + lc * 8;
        }
    }
    __bf16* dstA = (w < 4) ? &As[0][(w & 3) * 4096] : &Bs[0][(w & 3) * 4096];
    const int bufStride = 256 * 64;

    #define STAGE(bufsel, koff) do { \
        __bf16* d_ = dstA + (bufsel) * bufStride; \
        _Pragma("unroll") \
        for (int i_ = 0; i_ < 8; ++i_) gl2lds(ptr[i_] + (koff), d_ + i_ * 512); \
    } while (0)

    f32x4 acc[8][4];
    const f32x4 z = {0.f, 0.f, 0.f, 0.f};
    #pragma unroll
    for (int mi = 0; mi < 8; ++mi)
        #pragma unroll
        for (int nj = 0; nj < 4; ++nj) acc[mi][nj] = z;

    const int arow = (wm * 128 + l15) * 64;   // + mi*16*64
    const int brow = (wn * 64 + l15) * 64;    // + nj*16*64
    const int c0 = (q ^ l7) * 8, c1 = ((4 + q) ^ l7) * 8;

    STAGE(0, 0);
    STAGE(1, 64);
    int cur = 0;
    for (int kt = 0; kt < 16; ++kt) {
        if (kt < 15) asm volatile("s_waitcnt vmcnt(8)" ::: "memory");
        else         asm volatile("s_waitcnt vmcnt(0)" ::: "memory");
        __builtin_amdgcn_s_barrier();
        asm volatile("" ::: "memory");
        const __bf16* Ab = As[cur];
        const __bf16* Bb = Bs[cur];
        bf16x8 a0[8], b0[4];
        #pragma unroll
        for (int nj = 0; nj < 4; ++nj) b0[nj] = *(const bf16x8*)&Bb[brow + nj * 1024 + c0];
        #pragma unroll
        for (int mi = 0; mi < 8; ++mi) a0[mi] = *(const bf16x8*)&Ab[arow + mi * 1024 + c0];
        #pragma unroll
        for (int mi = 0; mi < 8; ++mi)
            #pragma unroll
            for (int nj = 0; nj < 4; ++nj)
                acc[mi][nj] = __builtin_amdgcn_mfma_f32_16x16x32_bf16(a0[mi], b0[nj], acc[mi][nj], 0, 0, 0);
        bf16x8 a1[8], b1[4];
        #pragma unroll
        for (int nj = 0; nj < 4; ++nj) b1[nj] = *(const bf16x8*)&Bb[brow + nj * 1024 + c1];
        #pragma unroll
        for (int mi = 0; mi < 8; ++mi) a1[mi] = *(const bf16x8*)&Ab[arow + mi * 1024 + c1];
        asm volatile("s_waitcnt lgkmcnt(0)" ::: "memory");
        __builtin_amdgcn_sched_barrier(0);
        __builtin_amdgcn_s_barrier();
        if (kt + 2 < 16) STAGE(cur, (kt + 2) * 64);
        __builtin_amdgcn_s_setprio(1);
        #pragma unroll
        for (int mi = 0; mi < 8; ++mi)
            #pragma unroll
            for (int nj = 0; nj < 4; ++nj)
                acc[mi][nj] = __builtin_amdgcn_mfma_f32_16x16x32_bf16(a1[mi], b1[nj], acc[mi][nj], 0, 0, 0);
        __builtin_amdgcn_s_setprio(0);
        cur ^= 1;
    }
    #undef STAGE

    const int abase = prefix[e];
    #pragma unroll
    for (int mi = 0; mi < 8; ++mi) {
        #pragma unroll
        for (int j = 0; j < 4; ++j) {
            const int grow = tileM * 256 + wm * 128 + mi * 16 + q * 4 + j;
            if (grow < count) {
                __bf16* arowp = act + (size_t)(abase + grow) * I_DIM + tileN * 128 + wn * 32 + l15;
                #pragma unroll
                for (int nj = 0; nj < 2; ++nj) {
                    const float v1 = acc[mi][nj][j];
                    const float v2 = acc[mi][nj + 2][j];
                    arowp[nj * 16] = (__bf16)(v1 / (1.f + __expf(-v1)) * v2);
                }
            }
        }
    }
}

// ======================= GEMM2 =======================
// 256 rows x 256 d-cols, K split in 2 halves of 1024 (grid z = e*2+h), BK=64,
// same pipeline; epilogue scatters gate*y with fp32 atomics.
__global__ __launch_bounds__(512) void gemm2_kernel(
    const __bf16* __restrict__ act, const __bf16* __restrict__ w2b,
    const int* __restrict__ counts, const int* __restrict__ prefix,
    const int* __restrict__ tok_list, const float* __restrict__ gate_list,
    float* __restrict__ out)
{
    const int e = blockIdx.z >> 1, h = blockIdx.z & 1;
    const int count = counts[e];
    const int tileM = blockIdx.x;
    if (tileM * 256 >= count) return;
    const int tileN = blockIdx.y;

    const int tid = threadIdx.x;
    const int lane = tid & 63, w = tid >> 6;
    const int l15 = lane & 15, q = lane >> 4, l7 = lane & 7;
    const int wm = w >> 2, wn = w & 3;
    const int abase = prefix[e];

    __shared__ __bf16 As[2][256 * 64];
    __shared__ __bf16 Bs[2][256 * 64];

    const int rl = lane >> 3;
    const int lc = (lane & 7) ^ rl;
    const __bf16* ptr[8];
    if (w < 4) {
        #pragma unroll
        for (int i = 0; i < 8; ++i) {
            const int r = tileM * 256 + w * 64 + i * 8 + rl;     // padded rows exist in act
            ptr[i] = act + (size_t)(abase + r) * I_DIM + h * 1024 + lc * 8;
        }
    } else {
        const int w4 = w - 4;
        #pragma unroll
        for (int i = 0; i < 8; ++i) {
            const int dcol = tileN * 256 + w4 * 64 + i * 8 + rl;
            ptr[i] = w2b + ((size_t)e * D_MODEL + dcol) * I_DIM + h * 1024 + lc * 8;
        }
    }
    __bf16* dstA = (w < 4) ? &As[0][(w & 3) * 4096] : &Bs[0][(w & 3) * 4096];
    const int bufStride = 256 * 64;

    #define STAGE(bufsel, koff) do { \
        __bf16* d_ = dstA + (bufsel) * bufStride; \
        _Pragma("unroll") \
        for (int i_ = 0; i_ < 8; ++i_) gl2lds(ptr[i_] + (koff), d_ + i_ * 512); \
    } while (0)

    f32x4 acc[8][4];
    const f32x4 z = {0.f, 0.f, 0.f, 0.f};
    #pragma unroll
    for (int mi = 0; mi < 8; ++mi)
        #pragma unroll
        for (int nj = 0; nj < 4; ++nj) acc[mi][nj] = z;

    const int arow = (wm * 128 + l15) * 64;
    const int brow = (wn * 64 + l15) * 64;
    const int c0 = (q ^ l7) * 8, c1 = ((4 + q) ^ l7) * 8;

    STAGE(0, 0);
    STAGE(1, 64);
    int cur = 0;
    for (int kt = 0; kt < 16; ++kt) {
        if (kt < 15) asm volatile("s_waitcnt vmcnt(8)" ::: "memory");
        else         asm volatile("s_waitcnt vmcnt(0)" ::: "memory");
        __builtin_amdgcn_s_barrier();
        asm volatile("" ::: "memory");
        const __bf16* Ab = As[cur];
        const __bf16* Bb = Bs[cur];
        bf16x8 a0[8], b0[4];
        #pragma unroll
        for (int nj = 0; nj < 4; ++nj) b0[nj] = *(const bf16x8*)&Bb[brow + nj * 1024 + c0];
        #pragma unroll
        for (int mi = 0; mi < 8; ++mi) a0[mi] = *(const bf16x8*)&Ab[arow + mi * 1024 + c0];
        #pragma unroll
        for (int mi = 0; mi < 8; ++mi)
            #pragma unroll
            for (int nj = 0; nj < 4; ++nj)
                acc[mi][nj] = __builtin_amdgcn_mfma_f32_16x16x32_bf16(a0[mi], b0[nj], acc[mi][nj], 0, 0, 0);
        bf16x8 a1[8], b1[4];
        #pragma unroll
        for (int nj = 0; nj < 4; ++nj) b1[nj] = *(const bf16x8*)&Bb[brow + nj * 1024 + c1];
        #pragma unroll
        for (int mi = 0; mi < 8; ++mi) a1[mi] = *(const bf16x8*)&Ab[arow + mi * 1024 + c1];
        asm volatile("s_waitcnt lgkmcnt(0)" ::: "memory");
        __builtin_amdgcn_sched_barrier(0);
        __builtin_amdgcn_s_barrier();
        if (kt + 2 < 16) STAGE(cur, (kt + 2) * 64);
        __builtin_amdgcn_s_setprio(1);
        #pragma unroll
        for (int mi = 0; mi < 8; ++mi)
            #pragma unroll
            for (int nj = 0; nj < 4; ++nj)
                acc[mi][nj] = __builtin_amdgcn_mfma_f32_16x16x32_bf16(a1[mi], b1[nj], acc[mi][nj], 0, 0, 0);
        __builtin_amdgcn_s_setprio(0);
        cur ^= 1;
    }
    #undef STAGE

    #pragma unroll
    for (int mi = 0; mi < 8; ++mi) {
        #pragma unroll
        for (int j = 0; j < 4; ++j) {
            const int grow = tileM * 256 + wm * 128 + mi * 16 + q * 4 + j;
            if (grow < count) {
                const int token = tok_list[e * T_TOK + grow];
                const float gate = gate_list[e * T_TOK + grow];
                float* orow = out + (size_t)token * D_MODEL + tileN * 256 + wn * 64 + l15;
                #pragma unroll
                for (int nj = 0; nj < 4; ++nj)
                    atomicAdd(orow + nj * 16, gate * acc[mi][nj][j]);
            }
        }
    }
}

extern "C" void kernel_launch(void* const* d_in, const int* in_sizes, int n_in,
                              void* d_out, int out_size, void* d_ws, size_t ws_size,
                              hipStream_t stream)
{
    const float* x   = (const float*)d_in[0];   // [4096, 1024]
    const float* rw  = (const float*)d_in[1];   // [16, 1024]
    const float* wsw = (const float*)d_in[2];   // [16, 4096, 1024]
    const float* w2s = (const float*)d_in[3];   // [16, 1024, 2048]
    float* out = (float*)d_out;                 // [4096, 1024] fp32

    char* wsb = (char*)d_ws;
    int* counts      = (int*)wsb;                                  // 64 B
    int* prefix      = (int*)(wsb + 128);                          // 17 ints
    int* tok_list    = (int*)(wsb + 1024);                         // 256 KB
    float* gate_list = (float*)(wsb + 1024 + E_EXP * T_TOK * 4);   // 256 KB
    __bf16* x_bf     = (__bf16*)(wsb + (1u << 20));                // [1, 9) MB
    __bf16* act      = (__bf16*)(wsb + (12u << 20));               // [12, ~96) MB (256-padded rows)
    __bf16* ws_bf    = (__bf16*)(wsb + (96u << 20));               // [96, 230) MB
    __bf16* w2_bf    = ws_bf;                                      // aliased: rewritten after gemm1

    hipMemsetAsync(counts, 0, E_EXP * sizeof(int), stream);
    hipMemsetAsync(d_out, 0, (size_t)out_size * sizeof(float), stream);

    router_kernel<<<dim3(T_TOK / 4), 256, 0, stream>>>(x, rw, counts, tok_list, gate_list);
    prefix_kernel<<<1, 64, 0, stream>>>(counts, prefix);

    cvt_kernel<<<2048, 256, 0, stream>>>(x, x_bf, T_TOK * D_MODEL / 8);
    cvt_kernel<<<8192, 256, 0, stream>>>(wsw, ws_bf, E_EXP * 2 * I_DIM * D_MODEL / 8);

    gemm1_kernel<<<dim3(8, I_DIM / 128, E_EXP), 512, 0, stream>>>(
        x_bf, ws_bf, counts, prefix, tok_list, act);

    cvt_kernel<<<8192, 256, 0, stream>>>(w2s, w2_bf, E_EXP * D_MODEL * I_DIM / 8);

    gemm2_kernel<<<dim3(8, D_MODEL / 256, E_EXP * 2), 512, 0, stream>>>(
        act, w2_bf, counts, prefix, tok_list, gate_list, out);
}

// Round 4
// 729.837 us; speedup vs baseline: 1.8405x; 1.1156x over previous
//
#include <hip/hip_runtime.h>
#include <hip/hip_bf16.h>

#define T_TOK 4096
#define D_MODEL 1024
#define I_DIM 2048
#define E_EXP 16

typedef __bf16 bf16x8 __attribute__((ext_vector_type(8)));
typedef float f32x4 __attribute__((ext_vector_type(4)));

__device__ __forceinline__ bf16x8 pack8(f32x4 a, f32x4 b) {
    bf16x8 r;
    r[0] = (__bf16)a[0]; r[1] = (__bf16)a[1]; r[2] = (__bf16)a[2]; r[3] = (__bf16)a[3];
    r[4] = (__bf16)b[0]; r[5] = (__bf16)b[1]; r[6] = (__bf16)b[2]; r[7] = (__bf16)b[3];
    return r;
}

__device__ __forceinline__ void gl2lds(const __bf16* src, __bf16* dst) {
    __builtin_amdgcn_global_load_lds(
        (const __attribute__((address_space(1))) unsigned int*)src,
        (__attribute__((address_space(3))) unsigned int*)dst, 16, 0, 0);
}

__global__ __launch_bounds__(256) void cvt_kernel(
    const float* __restrict__ in, __bf16* __restrict__ out, int n8)
{
    const int stride = gridDim.x * 256;
    for (int i = blockIdx.x * 256 + threadIdx.x; i < n8; i += stride) {
        f32x4 a = ((const f32x4*)in)[i * 2];
        f32x4 b = ((const f32x4*)in)[i * 2 + 1];
        ((bf16x8*)out)[i] = pack8(a, b);
    }
}

// ---------------- Router: fp64-accum logits, top-4, softmax-over-top4 ----------------
__global__ __launch_bounds__(256) void router_kernel(
    const float* __restrict__ x, const float* __restrict__ rw,
    int* __restrict__ counts, int* __restrict__ tok_list, float* __restrict__ gate_list)
{
    const int wid = threadIdx.x >> 6, lane = threadIdx.x & 63;
    const int t = blockIdx.x * 4 + wid;
    const int e = lane & 15, part = lane >> 4;

    const float* xr = x + (size_t)t * D_MODEL + part * 256;
    const float* wr = rw + (size_t)e * D_MODEL + part * 256;
    double acc = 0.0;
    #pragma unroll 4
    for (int i = 0; i < 256; i += 4) {
        f32x4 xv = *(const f32x4*)(xr + i);
        f32x4 wv = *(const f32x4*)(wr + i);
        acc += (double)xv[0] * wv[0] + (double)xv[1] * wv[1]
             + (double)xv[2] * wv[2] + (double)xv[3] * wv[3];
    }
    acc += __shfl_xor(acc, 16, 64);
    acc += __shfl_xor(acc, 32, 64);

    __shared__ float logits[4][16];
    if (lane < 16) logits[wid][lane] = (float)acc;
    __syncthreads();

    if (lane == 0) {
        float l[16];
        #pragma unroll
        for (int i = 0; i < 16; i++) l[i] = logits[wid][i];
        int idx[4]; float val[4];
        unsigned taken = 0;
        for (int k = 0; k < 4; k++) {
            int best = 0; float bv = -1e30f;
            for (int i = 0; i < 16; i++)
                if (!((taken >> i) & 1) && l[i] > bv) { bv = l[i]; best = i; }
            idx[k] = best; val[k] = bv; taken |= (1u << best);
        }
        float m = val[0];
        float w[4], s = 0.f;
        for (int k = 0; k < 4; k++) { w[k] = __expf(val[k] - m); s += w[k]; }
        for (int k = 0; k < 4; k++) {
            int ee = idx[k];
            int slot = atomicAdd(&counts[ee], 1);
            tok_list[ee * T_TOK + slot] = t;
            gate_list[ee * T_TOK + slot] = w[k] / s;
        }
    }
}

__global__ void prefix_kernel(const int* __restrict__ counts, int* __restrict__ prefix) {
    if (threadIdx.x == 0) {
        int acc = 0;
        for (int e = 0; e < E_EXP; e++) { prefix[e] = acc; acc += (counts[e] + 255) & ~255; }
        prefix[E_EXP] = acc;
    }
}

// ======================= GEMM1 + SwiGLU =======================
// 256 tokens x 256 B-rows (=128 act cols paired w1/v1), BK=64, 8 waves (2M x 4N).
// Counted-vmcnt 3-deep pipeline, 2 raw barriers/tile. 8-chunk XOR swizzle on
// both gl_lds SOURCE and ds_read addr (LDS itself linear [row][64]).
// XCD-chunked 1D grid: each expert's 128 blocks land consecutively on one XCD
// so panel-sharers co-reside and K-tile slices stay L2-resident.
__global__ __launch_bounds__(512) void gemm1_kernel(
    const __bf16* __restrict__ xb, const __bf16* __restrict__ wsb,
    const int* __restrict__ counts, const int* __restrict__ prefix,
    const int* __restrict__ tok_list, __bf16* __restrict__ act)
{
    const int q8 = gridDim.x >> 3;                       // blocks per XCD chunk
    const int lid = (blockIdx.x & 7) * q8 + (blockIdx.x >> 3);
    const int e = lid >> 7;                              // 128 blocks / expert
    const int r = lid & 127;
    const int tileM = r & 7;                             // tM fastest: B-sharers adjacent
    const int tileN = r >> 3;

    const int count = counts[e];
    if (tileM * 256 >= count) return;

    const int tid = threadIdx.x;
    const int lane = tid & 63, w = tid >> 6;
    const int l15 = lane & 15, q = lane >> 4, l7 = lane & 7;
    const int wm = w >> 2, wn = w & 3;

    __shared__ __bf16 As[2][256 * 64];
    __shared__ __bf16 Bs[2][256 * 64];

    const int rl = lane >> 3;               // row within 8-row issue group
    const int lc = (lane & 7) ^ rl;         // logical 16B chunk (swizzle involution)
    const __bf16* ptr[8];
    if (w < 4) {
        #pragma unroll
        for (int i = 0; i < 8; ++i) {
            int grow = tileM * 256 + w * 64 + i * 8 + rl;
            if (grow >= count) grow = count - 1;
            const int token = tok_list[e * T_TOK + grow];
            ptr[i] = xb + (size_t)token * D_MODEL + lc * 8;
        }
    } else {
        const int w4 = w - 4;
        #pragma unroll
        for (int i = 0; i < 8; ++i) {
            const int sub = i * 8 + rl;
            const int gcol = (sub < 32) ? (tileN * 128 + w4 * 32 + sub)
                                        : (I_DIM + tileN * 128 + w4 * 32 + (sub - 32));
            ptr[i] = wsb + ((size_t)e * 2 * I_DIM + gcol) * D_MODEL + lc * 8;
        }
    }
    __bf16* dstA = (w < 4) ? &As[0][(w & 3) * 4096] : &Bs[0][(w & 3) * 4096];
    const int bufStride = 256 * 64;

    #define STAGE(bufsel, koff) do { \
        __bf16* d_ = dstA + (bufsel) * bufStride; \
        _Pragma("unroll") \
        for (int i_ = 0; i_ < 8; ++i_) gl2lds(ptr[i_] + (koff), d_ + i_ * 512); \
    } while (0)

    f32x4 acc[8][4];
    const f32x4 z = {0.f, 0.f, 0.f, 0.f};
    #pragma unroll
    for (int mi = 0; mi < 8; ++mi)
        #pragma unroll
        for (int nj = 0; nj < 4; ++nj) acc[mi][nj] = z;

    const int arow = (wm * 128 + l15) * 64;   // + mi*16*64
    const int brow = (wn * 64 + l15) * 64;    // + nj*16*64
    const int c0 = (q ^ l7) * 8, c1 = ((4 + q) ^ l7) * 8;

    STAGE(0, 0);
    STAGE(1, 64);
    int cur = 0;
    for (int kt = 0; kt < 16; ++kt) {
        if (kt < 15) asm volatile("s_waitcnt vmcnt(8)" ::: "memory");
        else         asm volatile("s_waitcnt vmcnt(0)" ::: "memory");
        __builtin_amdgcn_s_barrier();
        asm volatile("" ::: "memory");
        const __bf16* Ab = As[cur];
        const __bf16* Bb = Bs[cur];
        bf16x8 a0[8], b0[4];
        #pragma unroll
        for (int nj = 0; nj < 4; ++nj) b0[nj] = *(const bf16x8*)&Bb[brow + nj * 1024 + c0];
        #pragma unroll
        for (int mi = 0; mi < 8; ++mi) a0[mi] = *(const bf16x8*)&Ab[arow + mi * 1024 + c0];
        #pragma unroll
        for (int mi = 0; mi < 8; ++mi)
            #pragma unroll
            for (int nj = 0; nj < 4; ++nj)
                acc[mi][nj] = __builtin_amdgcn_mfma_f32_16x16x32_bf16(a0[mi], b0[nj], acc[mi][nj], 0, 0, 0);
        bf16x8 a1[8], b1[4];
        #pragma unroll
        for (int nj = 0; nj < 4; ++nj) b1[nj] = *(const bf16x8*)&Bb[brow + nj * 1024 + c1];
        #pragma unroll
        for (int mi = 0; mi < 8; ++mi) a1[mi] = *(const bf16x8*)&Ab[arow + mi * 1024 + c1];
        asm volatile("s_waitcnt lgkmcnt(0)" ::: "memory");
        __builtin_amdgcn_sched_barrier(0);
        __builtin_amdgcn_s_barrier();
        if (kt + 2 < 16) STAGE(cur, (kt + 2) * 64);
        __builtin_amdgcn_s_setprio(1);
        #pragma unroll
        for (int mi = 0; mi < 8; ++mi)
            #pragma unroll
            for (int nj = 0; nj < 4; ++nj)
                acc[mi][nj] = __builtin_amdgcn_mfma_f32_16x16x32_bf16(a1[mi], b1[nj], acc[mi][nj], 0, 0, 0);
        __builtin_amdgcn_s_setprio(0);
        cur ^= 1;
    }
    #undef STAGE

    const int abase = prefix[e];
    #pragma unroll
    for (int mi = 0; mi < 8; ++mi) {
        #pragma unroll
        for (int j = 0; j < 4; ++j) {
            const int grow = tileM * 256 + wm * 128 + mi * 16 + q * 4 + j;
            if (grow < count) {
                __bf16* arowp = act + (size_t)(abase + grow) * I_DIM + tileN * 128 + wn * 32 + l15;
                #pragma unroll
                for (int nj = 0; nj < 2; ++nj) {
                    const float v1 = acc[mi][nj][j];
                    const float v2 = acc[mi][nj + 2][j];
                    arowp[nj * 16] = (__bf16)(v1 / (1.f + __expf(-v1)) * v2);
                }
            }
        }
    }
}

// ======================= GEMM2 =======================
// 256 rows x 256 d-cols, K split in 2 halves of 1024 (h), BK=64, same pipeline;
// epilogue scatters gate*y with fp32 atomics. XCD-chunked 1D grid (2 experts/XCD).
__global__ __launch_bounds__(512) void gemm2_kernel(
    const __bf16* __restrict__ act, const __bf16* __restrict__ w2b,
    const int* __restrict__ counts, const int* __restrict__ prefix,
    const int* __restrict__ tok_list, const float* __restrict__ gate_list,
    float* __restrict__ out)
{
    const int q8 = gridDim.x >> 3;
    const int lid = (blockIdx.x & 7) * q8 + (blockIdx.x >> 3);
    const int e = lid >> 6;                              // 64 blocks / expert
    const int r = lid & 63;
    const int h = r >> 5;
    const int rr = r & 31;
    const int tileM = rr & 7;
    const int tileN = rr >> 3;                           // 0..3

    const int count = counts[e];
    if (tileM * 256 >= count) return;

    const int tid = threadIdx.x;
    const int lane = tid & 63, w = tid >> 6;
    const int l15 = lane & 15, q = lane >> 4, l7 = lane & 7;
    const int wm = w >> 2, wn = w & 3;
    const int abase = prefix[e];

    __shared__ __bf16 As[2][256 * 64];
    __shared__ __bf16 Bs[2][256 * 64];

    const int rl = lane >> 3;
    const int lc = (lane & 7) ^ rl;
    const __bf16* ptr[8];
    if (w < 4) {
        #pragma unroll
        for (int i = 0; i < 8; ++i) {
            const int rw_ = tileM * 256 + w * 64 + i * 8 + rl;   // padded rows exist in act
            ptr[i] = act + (size_t)(abase + rw_) * I_DIM + h * 1024 + lc * 8;
        }
    } else {
        const int w4 = w - 4;
        #pragma unroll
        for (int i = 0; i < 8; ++i) {
            const int dcol = tileN * 256 + w4 * 64 + i * 8 + rl;
            ptr[i] = w2b + ((size_t)e * D_MODEL + dcol) * I_DIM + h * 1024 + lc * 8;
        }
    }
    __bf16* dstA = (w < 4) ? &As[0][(w & 3) * 4096] : &Bs[0][(w & 3) * 4096];
    const int bufStride = 256 * 64;

    #define STAGE(bufsel, koff) do { \
        __bf16* d_ = dstA + (bufsel) * bufStride; \
        _Pragma("unroll") \
        for (int i_ = 0; i_ < 8; ++i_) gl2lds(ptr[i_] + (koff), d_ + i_ * 512); \
    } while (0)

    f32x4 acc[8][4];
    const f32x4 z = {0.f, 0.f, 0.f, 0.f};
    #pragma unroll
    for (int mi = 0; mi < 8; ++mi)
        #pragma unroll
        for (int nj = 0; nj < 4; ++nj) acc[mi][nj] = z;

    const int arow = (wm * 128 + l15) * 64;
    const int brow = (wn * 64 + l15) * 64;
    const int c0 = (q ^ l7) * 8, c1 = ((4 + q) ^ l7) * 8;

    STAGE(0, 0);
    STAGE(1, 64);
    int cur = 0;
    for (int kt = 0; kt < 16; ++kt) {
        if (kt < 15) asm volatile("s_waitcnt vmcnt(8)" ::: "memory");
        else         asm volatile("s_waitcnt vmcnt(0)" ::: "memory");
        __builtin_amdgcn_s_barrier();
        asm volatile("" ::: "memory");
        const __bf16* Ab = As[cur];
        const __bf16* Bb = Bs[cur];
        bf16x8 a0[8], b0[4];
        #pragma unroll
        for (int nj = 0; nj < 4; ++nj) b0[nj] = *(const bf16x8*)&Bb[brow + nj * 1024 + c0];
        #pragma unroll
        for (int mi = 0; mi < 8; ++mi) a0[mi] = *(const bf16x8*)&Ab[arow + mi * 1024 + c0];
        #pragma unroll
        for (int mi = 0; mi < 8; ++mi)
            #pragma unroll
            for (int nj = 0; nj < 4; ++nj)
                acc[mi][nj] = __builtin_amdgcn_mfma_f32_16x16x32_bf16(a0[mi], b0[nj], acc[mi][nj], 0, 0, 0);
        bf16x8 a1[8], b1[4];
        #pragma unroll
        for (int nj = 0; nj < 4; ++nj) b1[nj] = *(const bf16x8*)&Bb[brow + nj * 1024 + c1];
        #pragma unroll
        for (int mi = 0; mi < 8; ++mi) a1[mi] = *(const bf16x8*)&Ab[arow + mi * 1024 + c1];
        asm volatile("s_waitcnt lgkmcnt(0)" ::: "memory");
        __builtin_amdgcn_sched_barrier(0);
        __builtin_amdgcn_s_barrier();
        if (kt + 2 < 16) STAGE(cur, (kt + 2) * 64);
        __builtin_amdgcn_s_setprio(1);
        #pragma unroll
        for (int mi = 0; mi < 8; ++mi)
            #pragma unroll
            for (int nj = 0; nj < 4; ++nj)
                acc[mi][nj] = __builtin_amdgcn_mfma_f32_16x16x32_bf16(a1[mi], b1[nj], acc[mi][nj], 0, 0, 0);
        __builtin_amdgcn_s_setprio(0);
        cur ^= 1;
    }
    #undef STAGE

    #pragma unroll
    for (int mi = 0; mi < 8; ++mi) {
        #pragma unroll
        for (int j = 0; j < 4; ++j) {
            const int grow = tileM * 256 + wm * 128 + mi * 16 + q * 4 + j;
            if (grow < count) {
                const int token = tok_list[e * T_TOK + grow];
                const float gate = gate_list[e * T_TOK + grow];
                float* orow = out + (size_t)token * D_MODEL + tileN * 256 + wn * 64 + l15;
                #pragma unroll
                for (int nj = 0; nj < 4; ++nj)
                    atomicAdd(orow + nj * 16, gate * acc[mi][nj][j]);
            }
        }
    }
}

extern "C" void kernel_launch(void* const* d_in, const int* in_sizes, int n_in,
                              void* d_out, int out_size, void* d_ws, size_t ws_size,
                              hipStream_t stream)
{
    const float* x   = (const float*)d_in[0];   // [4096, 1024]
    const float* rw  = (const float*)d_in[1];   // [16, 1024]
    const float* wsw = (const float*)d_in[2];   // [16, 4096, 1024]
    const float* w2s = (const float*)d_in[3];   // [16, 1024, 2048]
    float* out = (float*)d_out;                 // [4096, 1024] fp32

    char* wsb = (char*)d_ws;
    int* counts      = (int*)wsb;                                  // 64 B
    int* prefix      = (int*)(wsb + 128);                          // 17 ints
    int* tok_list    = (int*)(wsb + 1024);                         // 256 KB
    float* gate_list = (float*)(wsb + 1024 + E_EXP * T_TOK * 4);   // 256 KB
    __bf16* x_bf     = (__bf16*)(wsb + (1u << 20));                // [1, 9) MB
    __bf16* act      = (__bf16*)(wsb + (12u << 20));               // [12, ~96) MB (256-padded rows)
    __bf16* ws_bf    = (__bf16*)(wsb + (96u << 20));               // [96, 230) MB
    __bf16* w2_bf    = ws_bf;                                      // aliased: rewritten after gemm1

    hipMemsetAsync(counts, 0, E_EXP * sizeof(int), stream);
    hipMemsetAsync(d_out, 0, (size_t)out_size * sizeof(float), stream);

    router_kernel<<<dim3(T_TOK / 4), 256, 0, stream>>>(x, rw, counts, tok_list, gate_list);
    prefix_kernel<<<1, 64, 0, stream>>>(counts, prefix);

    cvt_kernel<<<2048, 256, 0, stream>>>(x, x_bf, T_TOK * D_MODEL / 8);
    cvt_kernel<<<8192, 256, 0, stream>>>(wsw, ws_bf, E_EXP * 2 * I_DIM * D_MODEL / 8);

    gemm1_kernel<<<dim3(2048), 512, 0, stream>>>(
        x_bf, ws_bf, counts, prefix, tok_list, act);

    cvt_kernel<<<8192, 256, 0, stream>>>(w2s, w2_bf, E_EXP * D_MODEL * I_DIM / 8);

    gemm2_kernel<<<dim3(1024), 512, 0, stream>>>(
        act, w2_bf, counts, prefix, tok_list, gate_list, out);
}